// Round 6
// baseline (796.331 us; speedup 1.0000x reference)
//
#include <hip/hip_runtime.h>
#include <hip/hip_bf16.h>
#include <math.h>

#define NN 50000
#define NE 800000
#define ET (NE + NN)
#define NG 512
#define NEG 0.2f

__device__ inline unsigned f2o(float f) {
    unsigned b = __float_as_uint(f);
    return (b & 0x80000000u) ? ~b : (b | 0x80000000u);
}
__device__ inline float o2f(unsigned u) {
    return (u & 0x80000000u) ? __uint_as_float(u ^ 0x80000000u) : __uint_as_float(~u);
}
__device__ inline unsigned short f2b(float f) {   // fp32 -> bf16 RNE
    unsigned u = __float_as_uint(f);
    u += 0x7fffu + ((u >> 16) & 1u);
    return (unsigned short)(u >> 16);
}
__device__ inline float b2f(unsigned short b) {
    return __uint_as_float(((unsigned)b) << 16);
}

// ---- GEMM: h = x @ W (M=NN, N=256), 128x128 tile, 8x8/thread --------------
// writes h in bf16; fused alpha_src/alpha_dst epilogue from fp32 accumulators
template<int K>
__global__ __launch_bounds__(256) void gemm_kernel(const float* __restrict__ x,
                                                   const float* __restrict__ W,
                                                   unsigned short* __restrict__ h,
                                                   const float* __restrict__ a_src,
                                                   const float* __restrict__ a_dst,
                                                   float* __restrict__ as_,
                                                   float* __restrict__ ad_) {
    __shared__ float As[16][132];
    __shared__ float Bs[16][132];
    const int t = threadIdx.x;
    const int tx = t & 15, ty = t >> 4;
    const int m0 = (blockIdx.x >> 1) * 128;
    const int n0 = (blockIdx.x & 1) * 128;
    float c[8][8] = {};
    const int lr = t >> 1;
    const int lk = (t & 1) * 8;
    const int br = t >> 4;
    const int bc = (t & 15) * 8;

    for (int k0 = 0; k0 < K; k0 += 16) {
        int ar = m0 + lr; if (ar >= NN) ar = NN - 1;
        float4 a0 = *(const float4*)&x[(long)ar * K + k0 + lk];
        float4 a1 = *(const float4*)&x[(long)ar * K + k0 + lk + 4];
        float4 b0 = *(const float4*)&W[(long)(k0 + br) * 256 + n0 + bc];
        float4 b1 = *(const float4*)&W[(long)(k0 + br) * 256 + n0 + bc + 4];
        __syncthreads();
        As[lk + 0][lr] = a0.x; As[lk + 1][lr] = a0.y;
        As[lk + 2][lr] = a0.z; As[lk + 3][lr] = a0.w;
        As[lk + 4][lr] = a1.x; As[lk + 5][lr] = a1.y;
        As[lk + 6][lr] = a1.z; As[lk + 7][lr] = a1.w;
        *(float4*)&Bs[br][bc]     = b0;
        *(float4*)&Bs[br][bc + 4] = b1;
        __syncthreads();
        #pragma unroll
        for (int kk = 0; kk < 16; ++kk) {
            float4 A0 = *(const float4*)&As[kk][ty * 4];
            float4 A1 = *(const float4*)&As[kk][64 + ty * 4];
            float4 B0 = *(const float4*)&Bs[kk][tx * 4];
            float4 B1 = *(const float4*)&Bs[kk][64 + tx * 4];
            float av[8] = {A0.x, A0.y, A0.z, A0.w, A1.x, A1.y, A1.z, A1.w};
            float bv[8] = {B0.x, B0.y, B0.z, B0.w, B1.x, B1.y, B1.z, B1.w};
            #pragma unroll
            for (int i = 0; i < 8; ++i)
                #pragma unroll
                for (int j = 0; j < 8; ++j)
                    c[i][j] = fmaf(av[i], bv[j], c[i][j]);
        }
    }

    const int hd0 = n0 >> 6, hd1 = hd0 + 1;
    float4 s0v = *(const float4*)&a_src[hd0 * 64 + tx * 4];
    float4 s1v = *(const float4*)&a_src[hd1 * 64 + tx * 4];
    float4 d0v = *(const float4*)&a_dst[hd0 * 64 + tx * 4];
    float4 d1v = *(const float4*)&a_dst[hd1 * 64 + tx * 4];
    #pragma unroll
    for (int half = 0; half < 2; ++half) {
        #pragma unroll
        for (int i = 0; i < 4; ++i) {
            int ai = half * 4 + i;
            int r = m0 + half * 64 + ty * 4 + i;
            float ps0 = c[ai][0]*s0v.x + c[ai][1]*s0v.y + c[ai][2]*s0v.z + c[ai][3]*s0v.w;
            float pd0 = c[ai][0]*d0v.x + c[ai][1]*d0v.y + c[ai][2]*d0v.z + c[ai][3]*d0v.w;
            float ps1 = c[ai][4]*s1v.x + c[ai][5]*s1v.y + c[ai][6]*s1v.z + c[ai][7]*s1v.w;
            float pd1 = c[ai][4]*d1v.x + c[ai][5]*d1v.y + c[ai][6]*d1v.z + c[ai][7]*d1v.w;
            #pragma unroll
            for (int off = 1; off < 16; off <<= 1) {
                ps0 += __shfl_xor(ps0, off, 64);
                pd0 += __shfl_xor(pd0, off, 64);
                ps1 += __shfl_xor(ps1, off, 64);
                pd1 += __shfl_xor(pd1, off, 64);
            }
            if (r < NN) {
                ushort4 v0 = {f2b(c[ai][0]), f2b(c[ai][1]), f2b(c[ai][2]), f2b(c[ai][3])};
                ushort4 v1 = {f2b(c[ai][4]), f2b(c[ai][5]), f2b(c[ai][6]), f2b(c[ai][7])};
                *(ushort4*)&h[(long)r * 256 + n0 + tx * 4]      = v0;
                *(ushort4*)&h[(long)r * 256 + n0 + 64 + tx * 4] = v1;
                if (tx == 0) {
                    as_[r * 4 + hd0] = ps0; ad_[r * 4 + hd0] = pd0;
                    as_[r * 4 + hd1] = ps1; ad_[r * 4 + hd1] = pd1;
                }
            }
        }
    }
}

// ---- global per-head max of alpha_src --------------------------------------
__global__ void gmax_init(unsigned* gmax) {
    if (threadIdx.x < 4) gmax[threadIdx.x] = 0u;
}
__global__ __launch_bounds__(256) void gmax_reduce(const float* __restrict__ as_,
                                                   unsigned* gmax) {
    float m0 = -1e30f, m1 = -1e30f, m2 = -1e30f, m3 = -1e30f;
    for (int n = blockIdx.x * 256 + threadIdx.x; n < NN; n += gridDim.x * 256) {
        float4 a = *(const float4*)&as_[n * 4];
        m0 = fmaxf(m0, a.x); m1 = fmaxf(m1, a.y);
        m2 = fmaxf(m2, a.z); m3 = fmaxf(m3, a.w);
    }
    #pragma unroll
    for (int off = 32; off; off >>= 1) {
        m0 = fmaxf(m0, __shfl_xor(m0, off, 64));
        m1 = fmaxf(m1, __shfl_xor(m1, off, 64));
        m2 = fmaxf(m2, __shfl_xor(m2, off, 64));
        m3 = fmaxf(m3, __shfl_xor(m3, off, 64));
    }
    __shared__ float sm[4][4];
    int lane = threadIdx.x & 63, w = threadIdx.x >> 6;
    if (lane == 0) { sm[w][0] = m0; sm[w][1] = m1; sm[w][2] = m2; sm[w][3] = m3; }
    __syncthreads();
    if (threadIdx.x == 0) {
        #pragma unroll
        for (int hd = 0; hd < 4; ++hd) {
            float mm = fmaxf(fmaxf(sm[0][hd], sm[1][hd]), fmaxf(sm[2][hd], sm[3][hd]));
            atomicMax(&gmax[hd], f2o(mm));
        }
    }
}

// ---- CSR-by-dst construction ----------------------------------------------
__global__ void init_counts(int* counts, int* esrc_pad) {
    int i = blockIdx.x * 256 + threadIdx.x;
    if (i < NN) counts[i] = 1;
    if (i < 16) esrc_pad[i] = 0;   // pad esrc[ET..ET+15] -> valid node 0
}
__global__ void count_kernel(const int* __restrict__ dst, int* counts) {
    int e = blockIdx.x * 256 + threadIdx.x;
    if (e < NE) atomicAdd(&counts[dst[e]], 1);
}
__global__ __launch_bounds__(1024) void scan_kernel(const int* __restrict__ counts,
                                                    int* row_ptr, int* cursor) {
    __shared__ int sm[1024];
    const int i = threadIdx.x;
    const int CH = (NN + 1023) / 1024;
    int base = i * CH;
    int s = 0;
    for (int j = 0; j < CH; ++j) { int idx = base + j; if (idx < NN) s += counts[idx]; }
    sm[i] = s; __syncthreads();
    for (int off = 1; off < 1024; off <<= 1) {
        int v = (i >= off) ? sm[i - off] : 0;
        __syncthreads();
        sm[i] += v;
        __syncthreads();
    }
    int run = sm[i] - s;
    for (int j = 0; j < CH; ++j) {
        int idx = base + j;
        if (idx < NN) { row_ptr[idx] = run; cursor[idx] = run; run += counts[idx]; }
    }
    if (i == 1023) row_ptr[NN] = ET;
}
__global__ void scatter_kernel(const int* __restrict__ src, const int* __restrict__ dst,
                               int* cursor, int* esrc) {
    int e = blockIdx.x * 256 + threadIdx.x;
    if (e < NE) {
        int p = atomicAdd(&cursor[dst[e]], 1);
        esrc[p] = src[e];
    } else if (e < ET) {
        int n = e - NE;
        int p = atomicAdd(&cursor[n], 1);
        esrc[p] = n;
    }
}

// ---- segment softmax + aggregation: one wave/node, bf16 payload,
// 2-deep software pipeline: no load depends on a same-iteration load --------
#define EDGE(ae, he)                                                           \
    {                                                                          \
        float t_ = (ae) + adn; t_ = t_ > 0.f ? t_ : NEG * t_;                  \
        float w_ = __expf(t_ - g); lsum += w_;                                 \
        acc.x = fmaf(w_, b2f((he).x), acc.x);                                  \
        acc.y = fmaf(w_, b2f((he).y), acc.y);                                  \
        acc.z = fmaf(w_, b2f((he).z), acc.z);                                  \
        acc.w = fmaf(w_, b2f((he).w), acc.w);                                  \
    }

template<int FINAL>
__global__ __launch_bounds__(256) void agg_kernel(const unsigned short* __restrict__ h,
        const float* __restrict__ as_, const float* __restrict__ ad_,
        const unsigned* __restrict__ gmax,
        const int* __restrict__ row_ptr, const int* __restrict__ esrc,
        const float* __restrict__ bias, float* __restrict__ out,
        const int* __restrict__ batch, const float* __restrict__ fcW) {
    int n = blockIdx.x * 4 + (threadIdx.x >> 6);
    int lane = threadIdx.x & 63;
    if (n >= NN) return;
    const int head = lane >> 4;
    const int c4 = lane * 4;
    int s0 = row_ptr[n], s1 = row_ptr[n + 1];
    float adn = ad_[n * 4 + head];
    float g = o2f(gmax[head]) + adn; g = g > 0.f ? g : NEG * g;
    float lsum = 0.f;
    float4 acc = {0.f, 0.f, 0.f, 0.f};

    int i = s0;
    // ---- prologue: indices for groups A and B, data for A (esrc padded +16)
    int iA0 = esrc[i],     iA1 = esrc[i + 1], iA2 = esrc[i + 2], iA3 = esrc[i + 3];
    int iB0 = esrc[i + 4], iB1 = esrc[i + 5], iB2 = esrc[i + 6], iB3 = esrc[i + 7];
    float aA0 = as_[iA0 * 4 + head], aA1 = as_[iA1 * 4 + head];
    float aA2 = as_[iA2 * 4 + head], aA3 = as_[iA3 * 4 + head];
    ushort4 hA0 = *(const ushort4*)&h[(long)iA0 * 256 + c4];
    ushort4 hA1 = *(const ushort4*)&h[(long)iA1 * 256 + c4];
    ushort4 hA2 = *(const ushort4*)&h[(long)iA2 * 256 + c4];
    ushort4 hA3 = *(const ushort4*)&h[(long)iA3 * 256 + c4];

    // ---- steady state: B-loads (idx 1 iter old) + C-indices, compute A ----
    while (i + 8 <= s1) {
        int iC0 = esrc[i + 8], iC1 = esrc[i + 9], iC2 = esrc[i + 10], iC3 = esrc[i + 11];
        float aB0 = as_[iB0 * 4 + head], aB1 = as_[iB1 * 4 + head];
        float aB2 = as_[iB2 * 4 + head], aB3 = as_[iB3 * 4 + head];
        ushort4 hB0 = *(const ushort4*)&h[(long)iB0 * 256 + c4];
        ushort4 hB1 = *(const ushort4*)&h[(long)iB1 * 256 + c4];
        ushort4 hB2 = *(const ushort4*)&h[(long)iB2 * 256 + c4];
        ushort4 hB3 = *(const ushort4*)&h[(long)iB3 * 256 + c4];
        EDGE(aA0, hA0); EDGE(aA1, hA1); EDGE(aA2, hA2); EDGE(aA3, hA3);
        iB0 = iC0; iB1 = iC1; iB2 = iC2; iB3 = iC3;
        aA0 = aB0; aA1 = aB1; aA2 = aB2; aA3 = aB3;
        hA0 = hB0; hA1 = hB1; hA2 = hB2; hA3 = hB3;
        i += 4;
    }
    // ---- epilogue: last full group already in registers -------------------
    if (i + 4 <= s1) {
        EDGE(aA0, hA0); EDGE(aA1, hA1); EDGE(aA2, hA2); EDGE(aA3, hA3);
        i += 4;
    }
    // ---- scalar tail (0..3 edges) -----------------------------------------
    for (; i < s1; ++i) {
        int s = esrc[i];
        float a = as_[s * 4 + head];
        ushort4 hv = *(const ushort4*)&h[(long)s * 256 + c4];
        EDGE(a, hv);
    }

    float rl = 1.f / lsum;
    float4 bv = *(const float4*)&bias[c4];
    float4 o = {fmaf(acc.x, rl, bv.x), fmaf(acc.y, rl, bv.y),
                fmaf(acc.z, rl, bv.z), fmaf(acc.w, rl, bv.w)};
    if (!FINAL) {
        *(float4*)&out[(long)n * 256 + c4] = o;
    } else {
        float4 fw = *(const float4*)&fcW[c4];
        float sd = o.x * fw.x + o.y * fw.y + o.z * fw.z + o.w * fw.w;
        #pragma unroll
        for (int off = 32; off; off >>= 1) sd += __shfl_xor(sd, off, 64);
        if (lane == 0) atomicAdd(&out[batch[n]], sd);
    }
}

// ---- output init ----------------------------------------------------------
__global__ void out_init(const float* __restrict__ fc_b, float* out) {
    int i = blockIdx.x * 256 + threadIdx.x;
    if (i < NG) out[i] = fc_b[0];
}

extern "C" void kernel_launch(void* const* d_in, const int* in_sizes, int n_in,
                              void* d_out, int out_size, void* d_ws, size_t ws_size,
                              hipStream_t stream) {
    const float* x      = (const float*)d_in[0];
    const int*   ei     = (const int*)d_in[1];
    const int*   batch  = (const int*)d_in[2];
    const float* W1     = (const float*)d_in[3];
    const float* as1    = (const float*)d_in[4];
    const float* ad1    = (const float*)d_in[5];
    const float* b1     = (const float*)d_in[6];
    const float* W2     = (const float*)d_in[7];
    const float* as2    = (const float*)d_in[8];
    const float* ad2    = (const float*)d_in[9];
    const float* b2     = (const float*)d_in[10];
    const float* W3     = (const float*)d_in[11];
    const float* as3    = (const float*)d_in[12];
    const float* ad3    = (const float*)d_in[13];
    const float* b3     = (const float*)d_in[14];
    const float* fcW    = (const float*)d_in[15];
    const float* fcb    = (const float*)d_in[16];
    const int* esrc_in = ei;
    const int* edst_in = ei + NE;

    char* ws = (char*)d_ws;
    size_t off = 0;
    unsigned short* hB = (unsigned short*)(ws + off); off += (size_t)NN * 256 * 2;
    float* aggF  = (float*)(ws + off); off += (size_t)NN * 256 * 4;
    float* aS    = (float*)(ws + off); off += (size_t)NN * 4 * 4;
    float* aD    = (float*)(ws + off); off += (size_t)NN * 4 * 4;
    int* counts  = (int*)(ws + off);   off += (size_t)NN * 4;
    int* cursor  = (int*)(ws + off);   off += (size_t)NN * 4;
    int* row_ptr = (int*)(ws + off);   off += (size_t)(NN + 1) * 4 + 12;
    unsigned* gmax = (unsigned*)(ws + off); off += 16;
    int* esrc    = (int*)(ws + off);   off += (size_t)(ET + 16) * 4;
    float* out   = (float*)d_out;

    // CSR by dst
    init_counts<<<(NN + 255) / 256, 256, 0, stream>>>(counts, esrc + ET);
    count_kernel<<<(NE + 255) / 256, 256, 0, stream>>>(edst_in, counts);
    scan_kernel<<<1, 1024, 0, stream>>>(counts, row_ptr, cursor);
    scatter_kernel<<<(ET + 255) / 256, 256, 0, stream>>>(esrc_in, edst_in, cursor, esrc);

    const int GEMM_GRID = ((NN + 127) / 128) * 2;
    const int NODE_GRID = (NN + 3) / 4;

    // layer 1
    gmax_init<<<1, 64, 0, stream>>>(gmax);
    gemm_kernel<128><<<GEMM_GRID, 256, 0, stream>>>(x, W1, hB, as1, ad1, aS, aD);
    gmax_reduce<<<128, 256, 0, stream>>>(aS, gmax);
    agg_kernel<0><<<NODE_GRID, 256, 0, stream>>>(hB, aS, aD, gmax, row_ptr, esrc, b1, aggF, nullptr, nullptr);
    // layer 2
    gmax_init<<<1, 64, 0, stream>>>(gmax);
    gemm_kernel<256><<<GEMM_GRID, 256, 0, stream>>>(aggF, W2, hB, as2, ad2, aS, aD);
    gmax_reduce<<<128, 256, 0, stream>>>(aS, gmax);
    agg_kernel<0><<<NODE_GRID, 256, 0, stream>>>(hB, aS, aD, gmax, row_ptr, esrc, b2, aggF, nullptr, nullptr);
    // layer 3 (agg fused with pooling + FC)
    gmax_init<<<1, 64, 0, stream>>>(gmax);
    gemm_kernel<256><<<GEMM_GRID, 256, 0, stream>>>(aggF, W3, hB, as3, ad3, aS, aD);
    gmax_reduce<<<128, 256, 0, stream>>>(aS, gmax);
    out_init<<<(NG + 255) / 256, 256, 0, stream>>>(fcb, out);
    agg_kernel<1><<<NODE_GRID, 256, 0, stream>>>(hB, aS, aD, gmax, row_ptr, esrc, b3, out, batch, fcW);
}

// Round 7
// 625.872 us; speedup vs baseline: 1.2724x; 1.2724x over previous
//
#include <hip/hip_runtime.h>
#include <hip/hip_bf16.h>
#include <math.h>

#define NN 50000
#define NE 800000
#define ET (NE + NN)
#define NG 512
#define NEG 0.2f

typedef __attribute__((ext_vector_type(8))) short bf16x8;
typedef __attribute__((ext_vector_type(4))) float f32x4;

__device__ inline unsigned f2o(float f) {
    unsigned b = __float_as_uint(f);
    return (b & 0x80000000u) ? ~b : (b | 0x80000000u);
}
__device__ inline float o2f(unsigned u) {
    return (u & 0x80000000u) ? __uint_as_float(u ^ 0x80000000u) : __uint_as_float(~u);
}
__device__ inline unsigned short f2b(float f) {   // fp32 -> bf16 RNE
    unsigned u = __float_as_uint(f);
    u += 0x7fffu + ((u >> 16) & 1u);
    return (unsigned short)(u >> 16);
}
__device__ inline float b2f(unsigned short b) {
    return __uint_as_float(((unsigned)b) << 16);
}

// ---- weight pre-transpose + hi/lo split: W[K][256] -> WT[256][K] ----------
__global__ __launch_bounds__(256) void split_weights(const float* __restrict__ W1,
        const float* __restrict__ W2, const float* __restrict__ W3,
        unsigned short* __restrict__ WTh, unsigned short* __restrict__ WTl) {
    int tid = blockIdx.x * 256 + threadIdx.x;
    const float* W; int K, n, k, base;
    if (tid < 32768)       { W = W1; K = 128; base = 0;     int i = tid;          n = i >> 7; k = i & 127; }
    else if (tid < 98304)  { W = W2; K = 256; base = 32768; int i = tid - 32768;  n = i >> 8; k = i & 255; }
    else if (tid < 163840) { W = W3; K = 256; base = 98304; int i = tid - 98304;  n = i >> 8; k = i & 255; }
    else return;
    float w = W[k * 256 + n];
    unsigned short hi = f2b(w);
    float lo = w - b2f(hi);
    WTh[base + n * K + k] = hi;
    WTl[base + n * K + k] = f2b(lo);
}

// ---- MFMA GEMM: C = A @ W  (M=NN, N=256), 128x128 tile, hi/lo bf16 --------
// A: fp32 (AFP32=1, converted in staging) or bf16 hi/lo pair.
// W passed pre-transposed [256][K] hi/lo. h written bf16; fused alpha epilogue.
template<int K, int AFP32>
__global__ __launch_bounds__(256) void gemm_mfma(const float* __restrict__ Af,
        const unsigned short* __restrict__ Ahi, const unsigned short* __restrict__ Alo,
        const unsigned short* __restrict__ Bhi, const unsigned short* __restrict__ Blo,
        unsigned short* __restrict__ h,
        const float* __restrict__ a_src, const float* __restrict__ a_dst,
        float* __restrict__ as_, float* __restrict__ ad_) {
    __shared__ unsigned short AsH[128][40], AsL[128][40], BsH[128][40], BsL[128][40];
    const int t = threadIdx.x;
    const int mb = blockIdx.x >> 1, nb = blockIdx.x & 1;
    const int m0 = mb * 128, n0 = nb * 128;
    const int wid = t >> 6, lane = t & 63;
    const int wr = wid >> 1, wc = wid & 1;
    const int lr = lane & 15, lg = lane >> 4;

    f32x4 acc[4][4];
    #pragma unroll
    for (int mi = 0; mi < 4; ++mi)
        #pragma unroll
        for (int ni = 0; ni < 4; ++ni)
            acc[mi][ni] = (f32x4){0.f, 0.f, 0.f, 0.f};

    for (int k0 = 0; k0 < K; k0 += 32) {
        __syncthreads();
        #pragma unroll
        for (int cc = 0; cc < 2; ++cc) {
            int c = t + cc * 256;
            int row = c >> 2, kc = c & 3;
            int gr = m0 + row; if (gr >= NN) gr = NN - 1;
            if (AFP32) {
                const float* pa = Af + (size_t)gr * K + k0 + kc * 8;
                float4 f0 = *(const float4*)pa;
                float4 f1 = *(const float4*)(pa + 4);
                union { unsigned short u[8]; uint4 v; } th, tl;
                float fs[8] = {f0.x, f0.y, f0.z, f0.w, f1.x, f1.y, f1.z, f1.w};
                #pragma unroll
                for (int j = 0; j < 8; ++j) {
                    unsigned short hv = f2b(fs[j]);
                    th.u[j] = hv;
                    tl.u[j] = f2b(fs[j] - b2f(hv));
                }
                *(uint4*)&AsH[row][kc * 8] = th.v;
                *(uint4*)&AsL[row][kc * 8] = tl.v;
            } else {
                *(uint4*)&AsH[row][kc * 8] = *(const uint4*)(Ahi + (size_t)gr * K + k0 + kc * 8);
                *(uint4*)&AsL[row][kc * 8] = *(const uint4*)(Alo + (size_t)gr * K + k0 + kc * 8);
            }
            *(uint4*)&BsH[row][kc * 8] = *(const uint4*)(Bhi + (size_t)(n0 + row) * K + k0 + kc * 8);
            *(uint4*)&BsL[row][kc * 8] = *(const uint4*)(Blo + (size_t)(n0 + row) * K + k0 + kc * 8);
        }
        __syncthreads();

        bf16x8 ah[4], al[4];
        #pragma unroll
        for (int mi = 0; mi < 4; ++mi) {
            int ra = wr * 64 + mi * 16 + lr;
            ah[mi] = *(const bf16x8*)&AsH[ra][lg * 8];
            al[mi] = *(const bf16x8*)&AsL[ra][lg * 8];
        }
        #pragma unroll
        for (int ni = 0; ni < 4; ++ni) {
            int rb = wc * 64 + ni * 16 + lr;
            bf16x8 bh = *(const bf16x8*)&BsH[rb][lg * 8];
            bf16x8 bl = *(const bf16x8*)&BsL[rb][lg * 8];
            #pragma unroll
            for (int mi = 0; mi < 4; ++mi) {
                // D^T = W-frag (A-op) x X-frag (B-op); acc row'=n, col'=m
                acc[mi][ni] = __builtin_amdgcn_mfma_f32_16x16x32_bf16(bh, ah[mi], acc[mi][ni], 0, 0, 0);
                acc[mi][ni] = __builtin_amdgcn_mfma_f32_16x16x32_bf16(bh, al[mi], acc[mi][ni], 0, 0, 0);
                acc[mi][ni] = __builtin_amdgcn_mfma_f32_16x16x32_bf16(bl, ah[mi], acc[mi][ni], 0, 0, 0);
            }
        }
    }

    // epilogue: h (bf16) + fused alpha dot products
    const int head = nb * 2 + wc;
    const int ncol0 = n0 + wc * 64;
    float4 asv[4], adv[4];
    #pragma unroll
    for (int ni = 0; ni < 4; ++ni) {
        asv[ni] = *(const float4*)&a_src[head * 64 + ni * 16 + lg * 4];
        adv[ni] = *(const float4*)&a_dst[head * 64 + ni * 16 + lg * 4];
    }
    #pragma unroll
    for (int mi = 0; mi < 4; ++mi) {
        float ps = 0.f, pd = 0.f;
        #pragma unroll
        for (int ni = 0; ni < 4; ++ni) {
            ps = fmaf(acc[mi][ni][0], asv[ni].x, ps); pd = fmaf(acc[mi][ni][0], adv[ni].x, pd);
            ps = fmaf(acc[mi][ni][1], asv[ni].y, ps); pd = fmaf(acc[mi][ni][1], adv[ni].y, pd);
            ps = fmaf(acc[mi][ni][2], asv[ni].z, ps); pd = fmaf(acc[mi][ni][2], adv[ni].z, pd);
            ps = fmaf(acc[mi][ni][3], asv[ni].w, ps); pd = fmaf(acc[mi][ni][3], adv[ni].w, pd);
        }
        ps += __shfl_xor(ps, 16, 64); ps += __shfl_xor(ps, 32, 64);
        pd += __shfl_xor(pd, 16, 64); pd += __shfl_xor(pd, 32, 64);
        int row = m0 + wr * 64 + mi * 16 + lr;
        if (row < NN) {
            #pragma unroll
            for (int ni = 0; ni < 4; ++ni) {
                ushort4 hv = {f2b(acc[mi][ni][0]), f2b(acc[mi][ni][1]),
                              f2b(acc[mi][ni][2]), f2b(acc[mi][ni][3])};
                *(ushort4*)&h[(size_t)row * 256 + ncol0 + ni * 16 + lg * 4] = hv;
            }
            if (lane < 16) { as_[row * 4 + head] = ps; ad_[row * 4 + head] = pd; }
        }
    }
}

// ---- global per-head max of alpha_src --------------------------------------
__global__ void gmax_init(unsigned* gmax) {
    if (threadIdx.x < 4) gmax[threadIdx.x] = 0u;
}
__global__ __launch_bounds__(256) void gmax_reduce(const float* __restrict__ as_,
                                                   unsigned* gmax) {
    float m0 = -1e30f, m1 = -1e30f, m2 = -1e30f, m3 = -1e30f;
    for (int n = blockIdx.x * 256 + threadIdx.x; n < NN; n += gridDim.x * 256) {
        float4 a = *(const float4*)&as_[n * 4];
        m0 = fmaxf(m0, a.x); m1 = fmaxf(m1, a.y);
        m2 = fmaxf(m2, a.z); m3 = fmaxf(m3, a.w);
    }
    #pragma unroll
    for (int off = 32; off; off >>= 1) {
        m0 = fmaxf(m0, __shfl_xor(m0, off, 64));
        m1 = fmaxf(m1, __shfl_xor(m1, off, 64));
        m2 = fmaxf(m2, __shfl_xor(m2, off, 64));
        m3 = fmaxf(m3, __shfl_xor(m3, off, 64));
    }
    __shared__ float sm[4][4];
    int lane = threadIdx.x & 63, w = threadIdx.x >> 6;
    if (lane == 0) { sm[w][0] = m0; sm[w][1] = m1; sm[w][2] = m2; sm[w][3] = m3; }
    __syncthreads();
    if (threadIdx.x == 0) {
        #pragma unroll
        for (int hd = 0; hd < 4; ++hd) {
            float mm = fmaxf(fmaxf(sm[0][hd], sm[1][hd]), fmaxf(sm[2][hd], sm[3][hd]));
            atomicMax(&gmax[hd], f2o(mm));
        }
    }
}

// ---- CSR-by-dst construction ----------------------------------------------
__global__ void init_counts(int* counts, int* esrc_pad) {
    int i = blockIdx.x * 256 + threadIdx.x;
    if (i < NN) counts[i] = 1;
    if (i < 16) esrc_pad[i] = 0;
}
__global__ void count_kernel(const int* __restrict__ dst, int* counts) {
    int e = blockIdx.x * 256 + threadIdx.x;
    if (e < NE) atomicAdd(&counts[dst[e]], 1);
}
__global__ __launch_bounds__(1024) void scan_kernel(const int* __restrict__ counts,
                                                    int* row_ptr, int* cursor) {
    __shared__ int sm[1024];
    const int i = threadIdx.x;
    const int CH = (NN + 1023) / 1024;
    int base = i * CH;
    int s = 0;
    for (int j = 0; j < CH; ++j) { int idx = base + j; if (idx < NN) s += counts[idx]; }
    sm[i] = s; __syncthreads();
    for (int off = 1; off < 1024; off <<= 1) {
        int v = (i >= off) ? sm[i - off] : 0;
        __syncthreads();
        sm[i] += v;
        __syncthreads();
    }
    int run = sm[i] - s;
    for (int j = 0; j < CH; ++j) {
        int idx = base + j;
        if (idx < NN) { row_ptr[idx] = run; cursor[idx] = run; run += counts[idx]; }
    }
    if (i == 1023) row_ptr[NN] = ET;
}
__global__ void scatter_kernel(const int* __restrict__ src, const int* __restrict__ dst,
                               int* cursor, int* esrc) {
    int e = blockIdx.x * 256 + threadIdx.x;
    if (e < NE) {
        int p = atomicAdd(&cursor[dst[e]], 1);
        esrc[p] = src[e];
    } else if (e < ET) {
        int n = e - NE;
        int p = atomicAdd(&cursor[n], 1);
        esrc[p] = n;
    }
}

// ---- segment softmax + aggregation: one wave/node, bf16 payload,
// 2-deep software pipeline; FINAL=0 writes hi/lo bf16 pair ------------------
#define EDGE(ae, he)                                                           \
    {                                                                          \
        float t_ = (ae) + adn; t_ = t_ > 0.f ? t_ : NEG * t_;                  \
        float w_ = __expf(t_ - g); lsum += w_;                                 \
        acc.x = fmaf(w_, b2f((he).x), acc.x);                                  \
        acc.y = fmaf(w_, b2f((he).y), acc.y);                                  \
        acc.z = fmaf(w_, b2f((he).z), acc.z);                                  \
        acc.w = fmaf(w_, b2f((he).w), acc.w);                                  \
    }

template<int FINAL>
__global__ __launch_bounds__(256) void agg_kernel(const unsigned short* __restrict__ h,
        const float* __restrict__ as_, const float* __restrict__ ad_,
        const unsigned* __restrict__ gmax,
        const int* __restrict__ row_ptr, const int* __restrict__ esrc,
        const float* __restrict__ bias,
        unsigned short* __restrict__ ohi, unsigned short* __restrict__ olo,
        float* __restrict__ out,
        const int* __restrict__ batch, const float* __restrict__ fcW) {
    int n = blockIdx.x * 4 + (threadIdx.x >> 6);
    int lane = threadIdx.x & 63;
    if (n >= NN) return;
    const int head = lane >> 4;
    const int c4 = lane * 4;
    int s0 = row_ptr[n], s1 = row_ptr[n + 1];
    float adn = ad_[n * 4 + head];
    float g = o2f(gmax[head]) + adn; g = g > 0.f ? g : NEG * g;
    float lsum = 0.f;
    float4 acc = {0.f, 0.f, 0.f, 0.f};

    int i = s0;
    int iA0 = esrc[i],     iA1 = esrc[i + 1], iA2 = esrc[i + 2], iA3 = esrc[i + 3];
    int iB0 = esrc[i + 4], iB1 = esrc[i + 5], iB2 = esrc[i + 6], iB3 = esrc[i + 7];
    float aA0 = as_[iA0 * 4 + head], aA1 = as_[iA1 * 4 + head];
    float aA2 = as_[iA2 * 4 + head], aA3 = as_[iA3 * 4 + head];
    ushort4 hA0 = *(const ushort4*)&h[(long)iA0 * 256 + c4];
    ushort4 hA1 = *(const ushort4*)&h[(long)iA1 * 256 + c4];
    ushort4 hA2 = *(const ushort4*)&h[(long)iA2 * 256 + c4];
    ushort4 hA3 = *(const ushort4*)&h[(long)iA3 * 256 + c4];

    while (i + 8 <= s1) {
        int iC0 = esrc[i + 8], iC1 = esrc[i + 9], iC2 = esrc[i + 10], iC3 = esrc[i + 11];
        float aB0 = as_[iB0 * 4 + head], aB1 = as_[iB1 * 4 + head];
        float aB2 = as_[iB2 * 4 + head], aB3 = as_[iB3 * 4 + head];
        ushort4 hB0 = *(const ushort4*)&h[(long)iB0 * 256 + c4];
        ushort4 hB1 = *(const ushort4*)&h[(long)iB1 * 256 + c4];
        ushort4 hB2 = *(const ushort4*)&h[(long)iB2 * 256 + c4];
        ushort4 hB3 = *(const ushort4*)&h[(long)iB3 * 256 + c4];
        EDGE(aA0, hA0); EDGE(aA1, hA1); EDGE(aA2, hA2); EDGE(aA3, hA3);
        iB0 = iC0; iB1 = iC1; iB2 = iC2; iB3 = iC3;
        aA0 = aB0; aA1 = aB1; aA2 = aB2; aA3 = aB3;
        hA0 = hB0; hA1 = hB1; hA2 = hB2; hA3 = hB3;
        i += 4;
    }
    if (i + 4 <= s1) {
        EDGE(aA0, hA0); EDGE(aA1, hA1); EDGE(aA2, hA2); EDGE(aA3, hA3);
        i += 4;
    }
    for (; i < s1; ++i) {
        int s = esrc[i];
        float a = as_[s * 4 + head];
        ushort4 hv = *(const ushort4*)&h[(long)s * 256 + c4];
        EDGE(a, hv);
    }

    float rl = 1.f / lsum;
    float4 bv = *(const float4*)&bias[c4];
    float4 o = {fmaf(acc.x, rl, bv.x), fmaf(acc.y, rl, bv.y),
                fmaf(acc.z, rl, bv.z), fmaf(acc.w, rl, bv.w)};
    if (!FINAL) {
        ushort4 vh = {f2b(o.x), f2b(o.y), f2b(o.z), f2b(o.w)};
        ushort4 vl = {f2b(o.x - b2f(vh.x)), f2b(o.y - b2f(vh.y)),
                      f2b(o.z - b2f(vh.z)), f2b(o.w - b2f(vh.w))};
        *(ushort4*)&ohi[(long)n * 256 + c4] = vh;
        *(ushort4*)&olo[(long)n * 256 + c4] = vl;
    } else {
        float4 fw = *(const float4*)&fcW[c4];
        float sd = o.x * fw.x + o.y * fw.y + o.z * fw.z + o.w * fw.w;
        #pragma unroll
        for (int off = 32; off; off >>= 1) sd += __shfl_xor(sd, off, 64);
        if (lane == 0) atomicAdd(&out[batch[n]], sd);
    }
}

// ---- output init ----------------------------------------------------------
__global__ void out_init(const float* __restrict__ fc_b, float* out) {
    int i = blockIdx.x * 256 + threadIdx.x;
    if (i < NG) out[i] = fc_b[0];
}

extern "C" void kernel_launch(void* const* d_in, const int* in_sizes, int n_in,
                              void* d_out, int out_size, void* d_ws, size_t ws_size,
                              hipStream_t stream) {
    const float* x      = (const float*)d_in[0];
    const int*   ei     = (const int*)d_in[1];
    const int*   batch  = (const int*)d_in[2];
    const float* W1     = (const float*)d_in[3];
    const float* as1    = (const float*)d_in[4];
    const float* ad1    = (const float*)d_in[5];
    const float* b1     = (const float*)d_in[6];
    const float* W2     = (const float*)d_in[7];
    const float* as2    = (const float*)d_in[8];
    const float* ad2    = (const float*)d_in[9];
    const float* b2     = (const float*)d_in[10];
    const float* W3     = (const float*)d_in[11];
    const float* as3    = (const float*)d_in[12];
    const float* ad3    = (const float*)d_in[13];
    const float* b3     = (const float*)d_in[14];
    const float* fcW    = (const float*)d_in[15];
    const float* fcb    = (const float*)d_in[16];
    const int* esrc_in = ei;
    const int* edst_in = ei + NE;

    char* ws = (char*)d_ws;
    size_t off = 0;
    unsigned short* hB  = (unsigned short*)(ws + off); off += (size_t)NN * 256 * 2;
    unsigned short* ohi = (unsigned short*)(ws + off); off += (size_t)NN * 256 * 2;
    unsigned short* olo = (unsigned short*)(ws + off); off += (size_t)NN * 256 * 2;
    unsigned short* WTh = (unsigned short*)(ws + off); off += 163840 * 2;
    unsigned short* WTl = (unsigned short*)(ws + off); off += 163840 * 2;
    float* aS    = (float*)(ws + off); off += (size_t)NN * 4 * 4;
    float* aD    = (float*)(ws + off); off += (size_t)NN * 4 * 4;
    int* counts  = (int*)(ws + off);   off += (size_t)NN * 4;
    int* cursor  = (int*)(ws + off);   off += (size_t)NN * 4;
    int* row_ptr = (int*)(ws + off);   off += (size_t)(NN + 1) * 4 + 12;
    unsigned* gmax = (unsigned*)(ws + off); off += 16;
    int* esrc    = (int*)(ws + off);   off += (size_t)(ET + 16) * 4;
    float* out   = (float*)d_out;

    // CSR by dst + weight split (graph/weights constant per call)
    init_counts<<<(NN + 255) / 256, 256, 0, stream>>>(counts, esrc + ET);
    count_kernel<<<(NE + 255) / 256, 256, 0, stream>>>(edst_in, counts);
    scan_kernel<<<1, 1024, 0, stream>>>(counts, row_ptr, cursor);
    scatter_kernel<<<(ET + 255) / 256, 256, 0, stream>>>(esrc_in, edst_in, cursor, esrc);
    split_weights<<<640, 256, 0, stream>>>(W1, W2, W3, WTh, WTl);

    const int GEMM_GRID = ((NN + 127) / 128) * 2;   // 391 * 2
    const int NODE_GRID = (NN + 3) / 4;

    // layer 1
    gmax_init<<<1, 64, 0, stream>>>(gmax);
    gemm_mfma<128, 1><<<GEMM_GRID, 256, 0, stream>>>(x, nullptr, nullptr, WTh, WTl, hB, as1, ad1, aS, aD);
    gmax_reduce<<<128, 256, 0, stream>>>(aS, gmax);
    agg_kernel<0><<<NODE_GRID, 256, 0, stream>>>(hB, aS, aD, gmax, row_ptr, esrc, b1, ohi, olo, nullptr, nullptr, nullptr);
    // layer 2
    gmax_init<<<1, 64, 0, stream>>>(gmax);
    gemm_mfma<256, 0><<<GEMM_GRID, 256, 0, stream>>>(nullptr, ohi, olo, WTh + 32768, WTl + 32768, hB, as2, ad2, aS, aD);
    gmax_reduce<<<128, 256, 0, stream>>>(aS, gmax);
    agg_kernel<0><<<NODE_GRID, 256, 0, stream>>>(hB, aS, aD, gmax, row_ptr, esrc, b2, ohi, olo, nullptr, nullptr, nullptr);
    // layer 3 (agg fused with pooling + FC)
    gmax_init<<<1, 64, 0, stream>>>(gmax);
    gemm_mfma<256, 0><<<GEMM_GRID, 256, 0, stream>>>(nullptr, ohi, olo, WTh + 98304, WTl + 98304, hB, as3, ad3, aS, aD);
    gmax_reduce<<<128, 256, 0, stream>>>(aS, gmax);
    out_init<<<(NG + 255) / 256, 256, 0, stream>>>(fcb, out);
    agg_kernel<1><<<NODE_GRID, 256, 0, stream>>>(hB, aS, aD, gmax, row_ptr, esrc, b3, nullptr, nullptr, out, batch, fcW);
}